// Round 1
// baseline (136.701 us; speedup 1.0000x reference)
//
#include <hip/hip_runtime.h>
#include <math.h>

#define V_ 2
#define C_ 128
#define H_ 64
#define W_ 128
#define D_ 32
#define HW_ (H_*W_)
#define PIXELS (V_*HW_)

#define PI_F 3.14159265358979323846f
#define TWO_PI_F 6.28318530717958647692f

// workspace layout (floats):
//   [0, V*HW*C)              transposed features T[v][h][w][c]  (8 MB)
//   [WS_POSE_OFF, +24)       poses[2] = {R row-major 9, t 3} each
//   [WS_DTAB_OFF, +64)       depth_tab[2][32]
#define WS_POSE_OFF (V_*HW_*C_)
#define WS_DTAB_OFF (WS_POSE_OFF + 24)

// ---------------- transpose (V,C,H,W) -> (V,H,W,C) ----------------
__global__ __launch_bounds__(256) void transpose_kernel(const float* __restrict__ f,
                                                        float* __restrict__ T) {
  __shared__ float tile[64][W_ + 1];
  int v  = blockIdx.x / H_;
  int h  = blockIdx.x % H_;
  int c0 = blockIdx.y * 64;
  int tw = threadIdx.x & (W_ - 1);   // 0..127
  int tc = threadIdx.x >> 7;         // 0..1
  const float* src = f + (((size_t)(v * C_ + c0)) * H_ + h) * W_;
#pragma unroll
  for (int c = tc; c < 64; c += 2)
    tile[c][tw] = src[(size_t)c * HW_ + tw];
  __syncthreads();
  int cc = threadIdx.x & 63;
  int w0 = threadIdx.x >> 6;         // 0..3
  float* dst = T + (((size_t)v * H_ + h) * W_) * C_ + c0;
#pragma unroll
  for (int w = w0; w < W_; w += 4)
    dst[(size_t)w * C_ + cc] = tile[cc][w];
}

// ---------------- pose + depth-candidate prep ----------------
__global__ void prep_kernel(const float* __restrict__ ex,
                            const float* __restrict__ nearp,
                            const float* __restrict__ farp,
                            float* __restrict__ pose_ws,
                            float* __restrict__ dtab) {
  int t = threadIdx.x;
  if (t < 64) {
    int n = t >> 5, j = t & 31;
    float mind = 1.f / farp[n];
    float maxd = 1.f / nearp[n];
    float lin  = (float)j / 31.f;
    dtab[t] = 1.f / (mind + lin * (maxd - mind));
  }
  if (t == 0) {
    // extrinsics (1,2,4,4) row-major: E0 = ex[0..15], E1 = ex[16..31]
    float R0[9], t0[3], R1[9], t1[3];
    for (int r = 0; r < 3; ++r) {
      for (int c = 0; c < 3; ++c) {
        R0[r*3+c] = ex[r*4 + c];
        R1[r*3+c] = ex[16 + r*4 + c];
      }
      t0[r] = ex[r*4 + 3];
      t1[r] = ex[16 + r*4 + 3];
    }
    // pose = inv(E1) @ E0 ; rigid: inv(E1) = [R1^T | -R1^T t1]
    // pose.R = R1^T R0 ; pose.t = R1^T (t0 - t1)
    float PR[9], PT[3];
    float d0 = t0[0]-t1[0], d1 = t0[1]-t1[1], d2 = t0[2]-t1[2];
    for (int i = 0; i < 3; ++i) {
      for (int c = 0; c < 3; ++c)
        PR[i*3+c] = R1[0*3+i]*R0[0*3+c] + R1[1*3+i]*R0[1*3+c] + R1[2*3+i]*R0[2*3+c];
      PT[i] = R1[0*3+i]*d0 + R1[1*3+i]*d1 + R1[2*3+i]*d2;
    }
    for (int i = 0; i < 9; ++i) pose_ws[i]     = PR[i];
    for (int i = 0; i < 3; ++i) pose_ws[9 + i] = PT[i];
    // poses[1] = inv(pose) = [PR^T | -PR^T PT]
    for (int r = 0; r < 3; ++r)
      for (int c = 0; c < 3; ++c)
        pose_ws[12 + r*3 + c] = PR[c*3 + r];
    for (int r = 0; r < 3; ++r)
      pose_ws[12 + 9 + r] = -(PR[0*3+r]*PT[0] + PR[1*3+r]*PT[1] + PR[2*3+r]*PT[2]);
  }
}

// ---------------- main correlation kernel ----------------
// one 64-lane wave per output pixel (n,h,w); lane holds channels {2*lane, 2*lane+1}
__global__ __launch_bounds__(256) void corr_kernel(const float* __restrict__ T,
                                                   const float* __restrict__ pose_ws,
                                                   const float* __restrict__ dtab,
                                                   float* __restrict__ out) {
  const int lane = threadIdx.x & 63;
  const int pix  = blockIdx.x * 4 + (threadIdx.x >> 6);
  const int n   = pix >> 13;        // / 8192
  const int rem = pix & 8191;
  const int h   = rem >> 7;
  const int w   = rem & 127;

  const float* F0 = T + (size_t)n       * HW_ * C_;
  const float* F1 = T + (size_t)(1 - n) * HW_ * C_;

  const float2 f0 = *(const float2*)(F0 + ((size_t)(h * W_ + w)) * C_ + (lane << 1));

  // ray direction for this pixel (wave-uniform)
  float theta = ((float)w + 0.5f) * (TWO_PI_F / (float)W_);
  float phi   = ((float)h + 0.5f) * (PI_F / (float)H_);
  float sphi = sinf(phi);
  float dx = sphi * sinf(theta);
  float dy = cosf(phi);
  float dz = sphi * cosf(theta);

  const float* P = pose_ws + n * 12;
  float rdx = P[0]*dx + P[1]*dy + P[2]*dz;
  float rdy = P[3]*dx + P[4]*dy + P[5]*dz;
  float rdz = P[6]*dx + P[7]*dy + P[8]*dz;
  float tx = P[9], ty = P[10], tz = P[11];

  // lane (d = lane&31) computes warp coords for its depth
  int dl = lane & 31;
  float depth = dtab[n * 32 + dl];
  float px = depth * rdx + tx;
  float py = depth * rdy + ty;
  float pz = depth * rdz + tz;
  float r = sqrtf(px*px + py*py + pz*pz);
  r = fmaxf(r, 0.001f);
  float cy = fminf(fmaxf(py / r, -1.f), 1.f);
  float phiw = acosf(cy);
  float thw = atan2f(px, pz);
  if (thw < 0.f) thw += TWO_PI_F;
  float u  = thw / TWO_PI_F * 2.f - 1.f;
  float vv = phiw / PI_F * 2.f - 1.f;
  float ix = (u  + 1.f) * 0.5f * (float)(W_ - 1);
  float iy = (vv + 1.f) * 0.5f * (float)(H_ - 1);

  float acc[32];
#pragma unroll
  for (int d = 0; d < 32; ++d) {
    float ixd = __shfl(ix, d, 64);
    float iyd = __shfl(iy, d, 64);
    float x0f = floorf(ixd), y0f = floorf(iyd);
    float x1f = x0f + 1.f,   y1f = y0f + 1.f;
    float wx1 = ixd - x0f, wx0 = 1.f - wx1;
    float wy1 = iyd - y0f, wy0 = 1.f - wy1;
    float vx0 = (x0f >= 0.f && x0f <= (float)(W_-1)) ? 1.f : 0.f;
    float vx1 = (x1f >= 0.f && x1f <= (float)(W_-1)) ? 1.f : 0.f;
    float vy0 = (y0f >= 0.f && y0f <= (float)(H_-1)) ? 1.f : 0.f;
    float vy1 = (y1f >= 0.f && y1f <= (float)(H_-1)) ? 1.f : 0.f;
    int xi0 = (int)fminf(fmaxf(x0f, 0.f), (float)(W_-1));
    int xi1 = (int)fminf(fmaxf(x1f, 0.f), (float)(W_-1));
    int yi0 = (int)fminf(fmaxf(y0f, 0.f), (float)(H_-1));
    int yi1 = (int)fminf(fmaxf(y1f, 0.f), (float)(H_-1));
    float w00 = wx0*wy0*vx0*vy0;
    float w10 = wx1*wy0*vx1*vy0;
    float w01 = wx0*wy1*vx0*vy1;
    float w11 = wx1*wy1*vx1*vy1;
    const int ch = lane << 1;
    float2 s00 = *(const float2*)(F1 + ((size_t)(yi0*W_ + xi0))*C_ + ch);
    float2 s10 = *(const float2*)(F1 + ((size_t)(yi0*W_ + xi1))*C_ + ch);
    float2 s01 = *(const float2*)(F1 + ((size_t)(yi1*W_ + xi0))*C_ + ch);
    float2 s11 = *(const float2*)(F1 + ((size_t)(yi1*W_ + xi1))*C_ + ch);
    float t00 = s00.x*f0.x + s00.y*f0.y;
    float t10 = s10.x*f0.x + s10.y*f0.y;
    float t01 = s01.x*f0.x + s01.y*f0.y;
    float t11 = s11.x*f0.x + s11.y*f0.y;
    acc[d] = w00*t00 + w10*t10 + w01*t01 + w11*t11;
  }

  // folded butterfly: 32 depth-sums over 64 lanes in 32 shuffles
  // after folds, lane L holds depth (L>>1); depth bit k-1 = lane bit k
  float a16[16];
#pragma unroll
  for (int j = 0; j < 16; ++j) {
    bool hi = (lane & 32) != 0;
    float keep = hi ? acc[j + 16] : acc[j];
    float send = hi ? acc[j] : acc[j + 16];
    a16[j] = keep + __shfl_xor(send, 32, 64);
  }
  float a8[8];
#pragma unroll
  for (int j = 0; j < 8; ++j) {
    bool hi = (lane & 16) != 0;
    float keep = hi ? a16[j + 8] : a16[j];
    float send = hi ? a16[j] : a16[j + 8];
    a8[j] = keep + __shfl_xor(send, 16, 64);
  }
  float a4[4];
#pragma unroll
  for (int j = 0; j < 4; ++j) {
    bool hi = (lane & 8) != 0;
    float keep = hi ? a8[j + 4] : a8[j];
    float send = hi ? a8[j] : a8[j + 4];
    a4[j] = keep + __shfl_xor(send, 8, 64);
  }
  float a2[2];
#pragma unroll
  for (int j = 0; j < 2; ++j) {
    bool hi = (lane & 4) != 0;
    float keep = hi ? a4[j + 2] : a4[j];
    float send = hi ? a4[j] : a4[j + 2];
    a2[j] = keep + __shfl_xor(send, 4, 64);
  }
  float v1;
  {
    bool hi = (lane & 2) != 0;
    float keep = hi ? a2[1] : a2[0];
    float send = hi ? a2[0] : a2[1];
    v1 = keep + __shfl_xor(send, 2, 64);
  }
  v1 += __shfl_xor(v1, 1, 64);

  if ((lane & 1) == 0) {
    int d = (lane >> 1) & 31;
    out[(((size_t)n * D_ + d) * H_ + h) * W_ + w] = v1 * 0.08838834764831845f; // 1/sqrt(128)
  }
}

extern "C" void kernel_launch(void* const* d_in, const int* in_sizes, int n_in,
                              void* d_out, int out_size, void* d_ws, size_t ws_size,
                              hipStream_t stream) {
  const float* features = (const float*)d_in[0];
  const float* extr     = (const float*)d_in[1];
  const float* nearp    = (const float*)d_in[2];
  const float* farp     = (const float*)d_in[3];
  float* out  = (float*)d_out;
  float* ws   = (float*)d_ws;
  float* T       = ws;
  float* pose_ws = ws + WS_POSE_OFF;
  float* dtab    = ws + WS_DTAB_OFF;

  hipLaunchKernelGGL(transpose_kernel, dim3(V_ * H_, 2), dim3(256), 0, stream, features, T);
  hipLaunchKernelGGL(prep_kernel, dim3(1), dim3(64), 0, stream, extr, nearp, farp, pose_ws, dtab);
  hipLaunchKernelGGL(corr_kernel, dim3(PIXELS / 4), dim3(256), 0, stream, T, pose_ws, dtab, out);
}

// Round 2
// 130.444 us; speedup vs baseline: 1.0480x; 1.0480x over previous
//
#include <hip/hip_runtime.h>
#include <math.h>

#define V_ 2
#define C_ 128
#define H_ 64
#define W_ 128
#define D_ 32
#define HW_ (H_*W_)
#define PIXELS (V_*HW_)

#define PI_F 3.14159265358979323846f
#define TWO_PI_F 6.28318530717958647692f

// workspace layout (floats): [0, V*HW*C) transposed features T[v][h][w][c] (8 MB)

// ---------------- transpose (V,C,H,W) -> (V,H,W,C) ----------------
// block b = ((v*64 + h)*2 + chalf); 256 threads; float2 global both sides
__global__ __launch_bounds__(256) void transpose_kernel(const float* __restrict__ f,
                                                        float* __restrict__ T) {
  __shared__ float tile[64][W_ + 2];   // pad 130: even row stride -> 8B-aligned pair writes
  const int b = blockIdx.x;
  const int chalf = b & 1;
  const int h = (b >> 1) & (H_ - 1);
  const int v = b >> 7;
  const int c0 = chalf * 64;
  const int t = threadIdx.x;

  const float* src = f + (((size_t)(v * C_ + c0)) * H_ + h) * W_;
  {
    const int w2 = t & 63;     // float2 index over w
    const int cb = t >> 6;     // 0..3
#pragma unroll
    for (int p = 0; p < 16; ++p) {
      const int c = cb + p * 4;
      const float2 x = *(const float2*)(src + (size_t)c * HW_ + w2 * 2);
      tile[c][w2 * 2]     = x.x;
      tile[c][w2 * 2 + 1] = x.y;
    }
  }
  __syncthreads();
  float* dst = T + (((size_t)v * H_ + h) * W_) * C_ + c0;
  {
    const int c2 = t & 31;     // channels {2*c2, 2*c2+1}
    const int w0 = t >> 5;     // 0..7
#pragma unroll
    for (int p = 0; p < 16; ++p) {
      const int w = w0 + p * 8;
      float2 o;
      o.x = tile[2 * c2][w];
      o.y = tile[2 * c2 + 1][w];
      *(float2*)(dst + (size_t)w * C_ + 2 * c2) = o;
    }
  }
}

__device__ __forceinline__ float rl_f(float x, int l) {
  return __int_as_float(__builtin_amdgcn_readlane(__float_as_int(x), l));
}

// ---------------- main correlation kernel ----------------
// one 64-lane wave per output pixel (n,h,w); lane holds channels {2*lane, 2*lane+1}
// lane (d = lane&31) precomputes warp params for depth d; loop broadcasts them
// via v_readlane -> SGPRs -> scalar-base loads + SGPR-operand FMAs.
__global__ __launch_bounds__(256) void corr_kernel(const float* __restrict__ T,
                                                   const float* __restrict__ ex,
                                                   const float* __restrict__ nearp,
                                                   const float* __restrict__ farp,
                                                   float* __restrict__ out) {
  const int lane = threadIdx.x & 63;
  const int pix  = blockIdx.x * 4 + (threadIdx.x >> 6);
  const int n   = pix >> 13;        // / 8192
  const int rem = pix & 8191;
  const int h   = rem >> 7;
  const int w   = rem & 127;

  const float* F0 = T + (size_t)n       * HW_ * C_;
  const float* F1 = T + (size_t)(1 - n) * HW_ * C_;
  const int ch = lane << 1;

  const float2 f0 = *(const float2*)(F0 + ((size_t)(h * W_ + w)) * C_ + ch);

  // ---- pose (wave-uniform; ex is tiny & cached) ----
  // pose0 = inv(E1) @ E0 (rigid): R = R1^T R0, t = R1^T (t0 - t1); pose1 = inv(pose0)
  float PR[9], PT[3];
  {
    float R0[9], R1[9];
#pragma unroll
    for (int r = 0; r < 3; ++r)
#pragma unroll
      for (int c = 0; c < 3; ++c) {
        R0[r * 3 + c] = ex[r * 4 + c];
        R1[r * 3 + c] = ex[16 + r * 4 + c];
      }
    const float d0 = ex[3]  - ex[19];
    const float d1 = ex[7]  - ex[23];
    const float d2 = ex[11] - ex[27];
#pragma unroll
    for (int i = 0; i < 3; ++i) {
#pragma unroll
      for (int c = 0; c < 3; ++c)
        PR[i * 3 + c] = R1[i] * R0[c] + R1[3 + i] * R0[3 + c] + R1[6 + i] * R0[6 + c];
      PT[i] = R1[i] * d0 + R1[3 + i] * d1 + R1[6 + i] * d2;
    }
  }
  float Rm[9], tv[3];
  if (n == 0) {
#pragma unroll
    for (int i = 0; i < 9; ++i) Rm[i] = PR[i];
#pragma unroll
    for (int i = 0; i < 3; ++i) tv[i] = PT[i];
  } else {
#pragma unroll
    for (int r = 0; r < 3; ++r)
#pragma unroll
      for (int c = 0; c < 3; ++c) Rm[r * 3 + c] = PR[c * 3 + r];
#pragma unroll
    for (int r = 0; r < 3; ++r)
      tv[r] = -(PR[r] * PT[0] + PR[3 + r] * PT[1] + PR[6 + r] * PT[2]);
  }

  // ---- ray direction (wave-uniform) ----
  const float theta = ((float)w + 0.5f) * (TWO_PI_F / (float)W_);
  const float phi   = ((float)h + 0.5f) * (PI_F / (float)H_);
  const float sphi = sinf(phi);
  const float dx_ = sphi * sinf(theta);
  const float dy_ = cosf(phi);
  const float dz_ = sphi * cosf(theta);
  const float rdx = Rm[0] * dx_ + Rm[1] * dy_ + Rm[2] * dz_;
  const float rdy = Rm[3] * dx_ + Rm[4] * dy_ + Rm[5] * dz_;
  const float rdz = Rm[6] * dx_ + Rm[7] * dy_ + Rm[8] * dz_;

  // ---- per-lane warp for depth dl = lane&31 ----
  const int dl = lane & 31;
  const float mind = 1.f / farp[n];
  const float maxd = 1.f / nearp[n];
  const float depth = 1.f / (mind + ((float)dl / 31.f) * (maxd - mind));
  const float px = depth * rdx + tv[0];
  const float py = depth * rdy + tv[1];
  const float pz = depth * rdz + tv[2];
  float r = sqrtf(px * px + py * py + pz * pz);
  r = fmaxf(r, 0.001f);
  const float cy = fminf(fmaxf(py / r, -1.f), 1.f);
  const float phiw = acosf(cy);
  float thw = atan2f(px, pz);
  if (thw < 0.f) thw += TWO_PI_F;
  const float ix = thw * ((float)(W_ - 1) / TWO_PI_F);
  const float iy = phiw * ((float)(H_ - 1) / PI_F);

  const float x0f = floorf(ix), y0f = floorf(iy);
  const float x1f = x0f + 1.f,  y1f = y0f + 1.f;
  const float wx1 = ix - x0f, wx0 = 1.f - wx1;
  const float wy1 = iy - y0f, wy0 = 1.f - wy1;
  const float vx0 = (x0f >= 0.f && x0f <= (float)(W_ - 1)) ? 1.f : 0.f;
  const float vx1 = (x1f >= 0.f && x1f <= (float)(W_ - 1)) ? 1.f : 0.f;
  const float vy0 = (y0f >= 0.f && y0f <= (float)(H_ - 1)) ? 1.f : 0.f;
  const float vy1 = (y1f >= 0.f && y1f <= (float)(H_ - 1)) ? 1.f : 0.f;
  const int xi0 = (int)fminf(fmaxf(x0f, 0.f), (float)(W_ - 1));
  const int xi1 = (int)fminf(fmaxf(x1f, 0.f), (float)(W_ - 1));
  const int yi0 = (int)fminf(fmaxf(y0f, 0.f), (float)(H_ - 1));
  const int yi1 = (int)fminf(fmaxf(y1f, 0.f), (float)(H_ - 1));
  const float w00l = wx0 * wy0 * vx0 * vy0;
  const float w10l = wx1 * wy0 * vx1 * vy0;
  const float w01l = wx0 * wy1 * vx0 * vy1;
  const float w11l = wx1 * wy1 * vx1 * vy1;
  // pack: bits 0..20 = (yi0*W+xi0)*C  (< 2^21), bit 30 = xstep, bit 31 = ystep
  const int packed = ((yi0 * W_ + xi0) * C_) | ((xi1 - xi0) << 30) | ((yi1 - yi0) << 31);

  float acc[32];
#pragma unroll
  for (int d = 0; d < 32; ++d) {
    const int pk  = __builtin_amdgcn_readlane(packed, d);
    const float w00 = rl_f(w00l, d);
    const float w10 = rl_f(w10l, d);
    const float w01 = rl_f(w01l, d);
    const float w11 = rl_f(w11l, d);
    const int bi  = pk & 0x3FFFFFFF & 0x001FFFFF;     // base element index
    const int dxo = (pk >> 23) & 128;                 // ((pk>>30)&1)*C
    const int dyo = (int)(((unsigned)pk >> 31) << 14);// ((pk>>31)&1)*W*C
    const float* p00 = F1 + bi;
    const float2 s00 = *(const float2*)(p00 + ch);
    const float2 s10 = *(const float2*)(p00 + dxo + ch);
    const float2 s01 = *(const float2*)(p00 + dyo + ch);
    const float2 s11 = *(const float2*)(p00 + (dxo + dyo) + ch);
    const float mx = w00 * s00.x + w10 * s10.x + w01 * s01.x + w11 * s11.x;
    const float my = w00 * s00.y + w10 * s10.y + w01 * s01.y + w11 * s11.y;
    acc[d] = mx * f0.x + my * f0.y;
  }

  // folded butterfly: 32 depth-sums over 64 lanes in 32 shuffles
  float a16[16];
#pragma unroll
  for (int j = 0; j < 16; ++j) {
    const bool hi = (lane & 32) != 0;
    const float keep = hi ? acc[j + 16] : acc[j];
    const float send = hi ? acc[j] : acc[j + 16];
    a16[j] = keep + __shfl_xor(send, 32, 64);
  }
  float a8[8];
#pragma unroll
  for (int j = 0; j < 8; ++j) {
    const bool hi = (lane & 16) != 0;
    const float keep = hi ? a16[j + 8] : a16[j];
    const float send = hi ? a16[j] : a16[j + 8];
    a8[j] = keep + __shfl_xor(send, 16, 64);
  }
  float a4[4];
#pragma unroll
  for (int j = 0; j < 4; ++j) {
    const bool hi = (lane & 8) != 0;
    const float keep = hi ? a4[0 * 0 + j + 4] * 0.f + (hi ? a8[j + 4] : a8[j]) : a8[j]; // (kept simple below)
    (void)keep;
    const float k2 = hi ? a8[j + 4] : a8[j];
    const float s2 = hi ? a8[j] : a8[j + 4];
    a4[j] = k2 + __shfl_xor(s2, 8, 64);
  }
  float a2[2];
#pragma unroll
  for (int j = 0; j < 2; ++j) {
    const bool hi = (lane & 4) != 0;
    const float k2 = hi ? a4[j + 2] : a4[j];
    const float s2 = hi ? a4[j] : a4[j + 2];
    a2[j] = k2 + __shfl_xor(s2, 4, 64);
  }
  float v1;
  {
    const bool hi = (lane & 2) != 0;
    const float k2 = hi ? a2[1] : a2[0];
    const float s2 = hi ? a2[0] : a2[1];
    v1 = k2 + __shfl_xor(s2, 2, 64);
  }
  v1 += __shfl_xor(v1, 1, 64);

  if ((lane & 1) == 0) {
    const int d = (lane >> 1) & 31;
    out[(((size_t)n * D_ + d) * H_ + h) * W_ + w] = v1 * 0.08838834764831845f; // 1/sqrt(128)
  }
}

extern "C" void kernel_launch(void* const* d_in, const int* in_sizes, int n_in,
                              void* d_out, int out_size, void* d_ws, size_t ws_size,
                              hipStream_t stream) {
  const float* features = (const float*)d_in[0];
  const float* extr     = (const float*)d_in[1];
  const float* nearp    = (const float*)d_in[2];
  const float* farp     = (const float*)d_in[3];
  float* out = (float*)d_out;
  float* T   = (float*)d_ws;

  hipLaunchKernelGGL(transpose_kernel, dim3(V_ * H_ * 2), dim3(256), 0, stream, features, T);
  hipLaunchKernelGGL(corr_kernel, dim3(PIXELS / 4), dim3(256), 0, stream,
                     T, extr, nearp, farp, out);
}

// Round 3
// 103.687 us; speedup vs baseline: 1.3184x; 1.2580x over previous
//
#include <hip/hip_runtime.h>
#include <math.h>

#define V_ 2
#define C_ 128
#define H_ 64
#define W_ 128
#define D_ 32
#define HW_ (H_*W_)
#define PIXELS (V_*HW_)

#define PI_F 3.14159265358979323846f
#define TWO_PI_F 6.28318530717958647692f

// workspace layout (floats): [0, V*HW*C) transposed features T[v][h][w][c] (8 MB)

// ---------------- transpose (V,C,H,W) -> (V,H,W,C) ----------------
__global__ __launch_bounds__(256) void transpose_kernel(const float* __restrict__ f,
                                                        float* __restrict__ T) {
  __shared__ float tile[64][W_ + 2];
  const int b = blockIdx.x;
  const int chalf = b & 1;
  const int h = (b >> 1) & (H_ - 1);
  const int v = b >> 7;
  const int c0 = chalf * 64;
  const int t = threadIdx.x;

  const float* src = f + (((size_t)(v * C_ + c0)) * H_ + h) * W_;
  {
    const int w2 = t & 63;
    const int cb = t >> 6;
#pragma unroll
    for (int p = 0; p < 16; ++p) {
      const int c = cb + p * 4;
      const float2 x = *(const float2*)(src + (size_t)c * HW_ + w2 * 2);
      tile[c][w2 * 2]     = x.x;
      tile[c][w2 * 2 + 1] = x.y;
    }
  }
  __syncthreads();
  float* dst = T + (((size_t)v * H_ + h) * W_) * C_ + c0;
  {
    const int c2 = t & 31;
    const int w0 = t >> 5;
#pragma unroll
    for (int p = 0; p < 16; ++p) {
      const int w = w0 + p * 8;
      float2 o;
      o.x = tile[2 * c2][w];
      o.y = tile[2 * c2 + 1][w];
      *(float2*)(dst + (size_t)w * C_ + 2 * c2) = o;
    }
  }
}

__device__ __forceinline__ float bperm_f(int byte_idx, float x) {
  return __int_as_float(__builtin_amdgcn_ds_bpermute(byte_idx, __float_as_int(x)));
}

// ---------------- main correlation kernel ----------------
// one 64-lane wave per output pixel. lane = (corner-group cg=lane>>5, channel
// quad cl=lane&31). Per depth: 2 dwordx4 loads cover all 4 bilinear corners
// (x-corners are channel-adjacent in (H,W,C) layout -> contiguous 1KB rows).
// Corner weights broadcast per-half via ds_bpermute; depth params via readlane.
// The 64-lane butterfly sums channels AND corners simultaneously.
__global__ __launch_bounds__(256, 4) void corr_kernel(const float* __restrict__ T,
                                                      const float* __restrict__ ex,
                                                      const float* __restrict__ nearp,
                                                      const float* __restrict__ farp,
                                                      float* __restrict__ out) {
  const int lane = threadIdx.x & 63;
  const int pix  = blockIdx.x * 4 + (threadIdx.x >> 6);
  const int n   = pix >> 13;
  const int rem = pix & 8191;
  const int h   = rem >> 7;
  const int w   = rem & 127;
  const int cg  = lane >> 5;      // corner group: 0 -> x0 column, 1 -> x1 column
  const int cl  = lane & 31;      // channel quad index

  const float* F0 = T + (size_t)n       * HW_ * C_;
  const float* F1 = T + (size_t)(1 - n) * HW_ * C_;

  const float4 f0v = *(const float4*)(F0 + ((size_t)(h * W_ + w)) * C_ + cl * 4);

  // ---- pose (wave-uniform) ----
  float PR[9], PT[3];
  {
    float R0[9], R1[9];
#pragma unroll
    for (int r = 0; r < 3; ++r)
#pragma unroll
      for (int c = 0; c < 3; ++c) {
        R0[r * 3 + c] = ex[r * 4 + c];
        R1[r * 3 + c] = ex[16 + r * 4 + c];
      }
    const float d0 = ex[3]  - ex[19];
    const float d1 = ex[7]  - ex[23];
    const float d2 = ex[11] - ex[27];
#pragma unroll
    for (int i = 0; i < 3; ++i) {
#pragma unroll
      for (int c = 0; c < 3; ++c)
        PR[i * 3 + c] = R1[i] * R0[c] + R1[3 + i] * R0[3 + c] + R1[6 + i] * R0[6 + c];
      PT[i] = R1[i] * d0 + R1[3 + i] * d1 + R1[6 + i] * d2;
    }
  }
  float Rm[9], tv[3];
  if (n == 0) {
#pragma unroll
    for (int i = 0; i < 9; ++i) Rm[i] = PR[i];
#pragma unroll
    for (int i = 0; i < 3; ++i) tv[i] = PT[i];
  } else {
#pragma unroll
    for (int r = 0; r < 3; ++r)
#pragma unroll
      for (int c = 0; c < 3; ++c) Rm[r * 3 + c] = PR[c * 3 + r];
#pragma unroll
    for (int r = 0; r < 3; ++r)
      tv[r] = -(PR[r] * PT[0] + PR[3 + r] * PT[1] + PR[6 + r] * PT[2]);
  }

  // ---- ray direction (wave-uniform) ----
  const float theta = ((float)w + 0.5f) * (TWO_PI_F / (float)W_);
  const float phi   = ((float)h + 0.5f) * (PI_F / (float)H_);
  const float sphi = sinf(phi);
  const float dx_ = sphi * sinf(theta);
  const float dy_ = cosf(phi);
  const float dz_ = sphi * cosf(theta);
  const float rdx = Rm[0] * dx_ + Rm[1] * dy_ + Rm[2] * dz_;
  const float rdy = Rm[3] * dx_ + Rm[4] * dy_ + Rm[5] * dz_;
  const float rdz = Rm[6] * dx_ + Rm[7] * dy_ + Rm[8] * dz_;

  // ---- per-lane warp for depth cl (both halves compute the same depth) ----
  const float mind = 1.f / farp[n];
  const float maxd = 1.f / nearp[n];
  const float depth = 1.f / (mind + ((float)cl / 31.f) * (maxd - mind));
  const float px = depth * rdx + tv[0];
  const float py = depth * rdy + tv[1];
  const float pz = depth * rdz + tv[2];
  float r = sqrtf(px * px + py * py + pz * pz);
  r = fmaxf(r, 0.001f);
  const float cy = fminf(fmaxf(py / r, -1.f), 1.f);
  const float phiw = acosf(cy);
  float thw = atan2f(px, pz);
  if (thw < 0.f) thw += TWO_PI_F;
  const float ix = thw * ((float)(W_ - 1) / TWO_PI_F);
  const float iy = phiw * ((float)(H_ - 1) / PI_F);

  const float x0f = floorf(ix), y0f = floorf(iy);
  const float x1f = x0f + 1.f,  y1f = y0f + 1.f;
  const float wx1 = ix - x0f, wx0 = 1.f - wx1;
  const float wy1 = iy - y0f, wy0 = 1.f - wy1;
  const float vx0 = (x0f >= 0.f && x0f <= (float)(W_ - 1)) ? 1.f : 0.f;
  const float vx1 = (x1f >= 0.f && x1f <= (float)(W_ - 1)) ? 1.f : 0.f;
  const float vy0 = (y0f >= 0.f && y0f <= (float)(H_ - 1)) ? 1.f : 0.f;
  const float vy1 = (y1f >= 0.f && y1f <= (float)(H_ - 1)) ? 1.f : 0.f;
  const int xi0 = (int)fminf(fmaxf(x0f, 0.f), (float)(W_ - 1));
  const int xi1 = (int)fminf(fmaxf(x1f, 0.f), (float)(W_ - 1));
  const int yi0 = (int)fminf(fmaxf(y0f, 0.f), (float)(H_ - 1));
  const int yi1 = (int)fminf(fmaxf(y1f, 0.f), (float)(H_ - 1));
  const float w00 = wx0 * wy0 * vx0 * vy0;
  const float w10 = wx1 * wy0 * vx1 * vy0;
  const float w01 = wx0 * wy1 * vx0 * vy1;
  const float w11 = wx1 * wy1 * vx1 * vy1;
  // per-half weight tables: lanes 0..31 hold x0-column weights for depth cl,
  // lanes 32..63 hold x1-column weights for depth cl
  const float wA_pre = cg ? w10 : w00;   // row y0
  const float wB_pre = cg ? w11 : w01;   // row y1
  // pack: bits 0..19 = (yi0*W+xi0)*C (element idx), bit 30 = xstep, bit 31 = ystep
  const int packed = ((yi0 * W_ + xi0) * C_) | ((xi1 - xi0) << 30) | ((yi1 - yi0) << 31);

  const int choff_b  = cl * 16;    // byte offset of this lane's channel quad
  const int permbase = cg * 128;   // bpermute byte base: upper half reads lanes 32+d

  float acc[32];
#pragma unroll
  for (int d = 0; d < 32; ++d) {
    const int pk = __builtin_amdgcn_readlane(packed, d);
    const int bi    = pk & 0x000FFFFF;               // base element index (512B-aligned*4)
    const int dxo_b = (int)(((unsigned)pk >> 21) & 512u);     // xstep * C * 4 bytes
    const int dyo_b = (int)(((unsigned)pk >> 31) << 16);      // ystep * W * C * 4 bytes
    const char* baseA = (const char*)(F1 + bi);
    const int vt   = choff_b + dxo_b;
    const int voff = cg ? vt : choff_b;              // x1 column lanes add dxo
    const float4 sA = *(const float4*)(baseA + voff);                 // row y0
    const float4 sB = *(const float4*)(baseA + (dyo_b + voff));       // row y1
    const float wa = bperm_f(permbase + d * 4, wA_pre);
    const float wb = bperm_f(permbase + d * 4, wB_pre);
    const float dota = sA.x * f0v.x + sA.y * f0v.y + sA.z * f0v.z + sA.w * f0v.w;
    const float dotb = sB.x * f0v.x + sB.y * f0v.y + sB.z * f0v.z + sB.w * f0v.w;
    acc[d] = wa * dota + wb * dotb;
  }

  // folded butterfly: 32 depth-sums over 64 lanes (channels x corners) in 63 shuffles
  float a16[16];
#pragma unroll
  for (int j = 0; j < 16; ++j) {
    const bool hi = (lane & 32) != 0;
    const float keep = hi ? acc[j + 16] : acc[j];
    const float send = hi ? acc[j] : acc[j + 16];
    a16[j] = keep + __shfl_xor(send, 32, 64);
  }
  float a8[8];
#pragma unroll
  for (int j = 0; j < 8; ++j) {
    const bool hi = (lane & 16) != 0;
    const float keep = hi ? a16[j + 8] : a16[j];
    const float send = hi ? a16[j] : a16[j + 8];
    a8[j] = keep + __shfl_xor(send, 16, 64);
  }
  float a4[4];
#pragma unroll
  for (int j = 0; j < 4; ++j) {
    const bool hi = (lane & 8) != 0;
    const float keep = hi ? a8[j + 4] : a8[j];
    const float send = hi ? a8[j] : a8[j + 4];
    a4[j] = keep + __shfl_xor(send, 8, 64);
  }
  float a2[2];
#pragma unroll
  for (int j = 0; j < 2; ++j) {
    const bool hi = (lane & 4) != 0;
    const float keep = hi ? a4[j + 2] : a4[j];
    const float send = hi ? a4[j] : a4[j + 2];
    a2[j] = keep + __shfl_xor(send, 4, 64);
  }
  float v1;
  {
    const bool hi = (lane & 2) != 0;
    const float keep = hi ? a2[1] : a2[0];
    const float send = hi ? a2[0] : a2[1];
    v1 = keep + __shfl_xor(send, 2, 64);
  }
  v1 += __shfl_xor(v1, 1, 64);

  if ((lane & 1) == 0) {
    const int d = (lane >> 1) & 31;
    out[(((size_t)n * D_ + d) * H_ + h) * W_ + w] = v1 * 0.08838834764831845f; // 1/sqrt(128)
  }
}

extern "C" void kernel_launch(void* const* d_in, const int* in_sizes, int n_in,
                              void* d_out, int out_size, void* d_ws, size_t ws_size,
                              hipStream_t stream) {
  const float* features = (const float*)d_in[0];
  const float* extr     = (const float*)d_in[1];
  const float* nearp    = (const float*)d_in[2];
  const float* farp     = (const float*)d_in[3];
  float* out = (float*)d_out;
  float* T   = (float*)d_ws;

  hipLaunchKernelGGL(transpose_kernel, dim3(V_ * H_ * 2), dim3(256), 0, stream, features, T);
  hipLaunchKernelGGL(corr_kernel, dim3(PIXELS / 4), dim3(256), 0, stream,
                     T, extr, nearp, farp, out);
}

// Round 4
// 91.109 us; speedup vs baseline: 1.5004x; 1.1381x over previous
//
#include <hip/hip_runtime.h>
#include <math.h>

#define V_ 2
#define C_ 128
#define H_ 64
#define W_ 128
#define D_ 32
#define HW_ (H_*W_)
#define PIXELS (V_*HW_)

#define PI_F 3.14159265358979323846f
#define TWO_PI_F 6.28318530717958647692f

typedef _Float16 half2_t __attribute__((ext_vector_type(2)));
typedef _Float16 half8_t __attribute__((ext_vector_type(8)));

// workspace: T = f16 features, layout (V,H,W,C), 4 MB

__device__ __forceinline__ float fdot2f(half2_t a, half2_t b, float c) {
#if __has_builtin(__builtin_amdgcn_fdot2)
  return __builtin_amdgcn_fdot2(a, b, c, false);
#else
  return (float)a[0] * (float)b[0] + ((float)a[1] * (float)b[1] + c);
#endif
}

// ---------------- transpose (V,C,H,W) fp32 -> (V,H,W,C) f16 ----------------
__global__ __launch_bounds__(256) void transpose_kernel(const float* __restrict__ f,
                                                        _Float16* __restrict__ T) {
  __shared__ float tile[64][W_ + 2];
  const int b = blockIdx.x;
  const int chalf = b & 1;
  const int h = (b >> 1) & (H_ - 1);
  const int v = b >> 7;
  const int c0 = chalf * 64;
  const int t = threadIdx.x;

  const float* src = f + (((size_t)(v * C_ + c0)) * H_ + h) * W_;
  {
    const int w2 = t & 63;
    const int cb = t >> 6;
#pragma unroll
    for (int p = 0; p < 16; ++p) {
      const int c = cb + p * 4;
      const float2 x = *(const float2*)(src + (size_t)c * HW_ + w2 * 2);
      tile[c][w2 * 2]     = x.x;
      tile[c][w2 * 2 + 1] = x.y;
    }
  }
  __syncthreads();
  _Float16* dst = T + (((size_t)v * H_ + h) * W_) * C_ + c0;
  {
    const int c2 = t & 31;
    const int w0 = t >> 5;
#pragma unroll
    for (int p = 0; p < 16; ++p) {
      const int w = w0 + p * 8;
      half2_t o;
      o[0] = (_Float16)tile[2 * c2][w];
      o[1] = (_Float16)tile[2 * c2 + 1][w];
      *(half2_t*)(dst + (size_t)w * C_ + 2 * c2) = o;
    }
  }
}

__device__ __forceinline__ float bperm_f(int byte_idx, float x) {
  return __int_as_float(__builtin_amdgcn_ds_bpermute(byte_idx, __float_as_int(x)));
}

// ---------------- main correlation kernel ----------------
// one 64-lane wave per output pixel. lane = (corner c=lane>>4 [bit4=x,bit5=y],
// channel-oct cl=lane&15). Per depth: ONE dwordx4 wave-load covers all 4
// bilinear corners (f16: pixel vec = 256B; x0/x1 contiguous 512B; y-row pair
// via per-lane dyo). Dot via v_dot2_f32_f16. Weights applied AFTER the
// channel-bit butterfly (4 bpermutes total), then corner bits fold.
__global__ __launch_bounds__(256, 4) void corr_kernel(const _Float16* __restrict__ T,
                                                      const float* __restrict__ ex,
                                                      const float* __restrict__ nearp,
                                                      const float* __restrict__ farp,
                                                      float* __restrict__ out) {
  const int lane = threadIdx.x & 63;
  const int pix  = blockIdx.x * 4 + (threadIdx.x >> 6);
  const int n   = pix >> 13;
  const int rem = pix & 8191;
  const int h   = rem >> 7;
  const int w   = rem & 127;
  const int cl  = lane & 15;          // channel oct
  const unsigned mx = ((lane >> 4) & 1) ? 0xFFFFFFFFu : 0u;  // x1 column lanes
  const unsigned my = (lane >= 32)     ? 0xFFFFFFFFu : 0u;   // y1 row lanes

  const char* F0b = (const char*)(T + (size_t)n       * HW_ * C_);
  const char* F1b = (const char*)(T + (size_t)(1 - n) * HW_ * C_);

  const half8_t f0v = *(const half8_t*)(F0b + ((size_t)(h * W_ + w)) * 256 + cl * 16);
  const half2_t f0a = __builtin_shufflevector(f0v, f0v, 0, 1);
  const half2_t f0b_ = __builtin_shufflevector(f0v, f0v, 2, 3);
  const half2_t f0c = __builtin_shufflevector(f0v, f0v, 4, 5);
  const half2_t f0d = __builtin_shufflevector(f0v, f0v, 6, 7);

  // ---- pose (wave-uniform) ----
  float PR[9], PT[3];
  {
    float R0[9], R1[9];
#pragma unroll
    for (int r = 0; r < 3; ++r)
#pragma unroll
      for (int c = 0; c < 3; ++c) {
        R0[r * 3 + c] = ex[r * 4 + c];
        R1[r * 3 + c] = ex[16 + r * 4 + c];
      }
    const float d0 = ex[3]  - ex[19];
    const float d1 = ex[7]  - ex[23];
    const float d2 = ex[11] - ex[27];
#pragma unroll
    for (int i = 0; i < 3; ++i) {
#pragma unroll
      for (int c = 0; c < 3; ++c)
        PR[i * 3 + c] = R1[i] * R0[c] + R1[3 + i] * R0[3 + c] + R1[6 + i] * R0[6 + c];
      PT[i] = R1[i] * d0 + R1[3 + i] * d1 + R1[6 + i] * d2;
    }
  }
  float Rm[9], tv[3];
  if (n == 0) {
#pragma unroll
    for (int i = 0; i < 9; ++i) Rm[i] = PR[i];
#pragma unroll
    for (int i = 0; i < 3; ++i) tv[i] = PT[i];
  } else {
#pragma unroll
    for (int r = 0; r < 3; ++r)
#pragma unroll
      for (int c = 0; c < 3; ++c) Rm[r * 3 + c] = PR[c * 3 + r];
#pragma unroll
    for (int r = 0; r < 3; ++r)
      tv[r] = -(PR[r] * PT[0] + PR[3 + r] * PT[1] + PR[6 + r] * PT[2]);
  }

  // ---- ray direction (wave-uniform) ----
  const float theta = ((float)w + 0.5f) * (TWO_PI_F / (float)W_);
  const float phi   = ((float)h + 0.5f) * (PI_F / (float)H_);
  const float sphi = sinf(phi);
  const float dx_ = sphi * sinf(theta);
  const float dy_ = cosf(phi);
  const float dz_ = sphi * cosf(theta);
  const float rdx = Rm[0] * dx_ + Rm[1] * dy_ + Rm[2] * dz_;
  const float rdy = Rm[3] * dx_ + Rm[4] * dy_ + Rm[5] * dz_;
  const float rdz = Rm[6] * dx_ + Rm[7] * dy_ + Rm[8] * dz_;

  // ---- per-lane warp for depth dl = lane&31 ----
  const int dl = lane & 31;
  const float mind = 1.f / farp[n];
  const float maxd = 1.f / nearp[n];
  const float depth = 1.f / (mind + ((float)dl / 31.f) * (maxd - mind));
  const float px = depth * rdx + tv[0];
  const float py = depth * rdy + tv[1];
  const float pz = depth * rdz + tv[2];
  float r = sqrtf(px * px + py * py + pz * pz);
  r = fmaxf(r, 0.001f);
  const float cy = fminf(fmaxf(py / r, -1.f), 1.f);
  const float phiw = acosf(cy);
  float thw = atan2f(px, pz);
  if (thw < 0.f) thw += TWO_PI_F;
  const float ix = thw * ((float)(W_ - 1) / TWO_PI_F);
  const float iy = phiw * ((float)(H_ - 1) / PI_F);

  const float x0f = floorf(ix), y0f = floorf(iy);
  const float x1f = x0f + 1.f,  y1f = y0f + 1.f;
  const float wx1 = ix - x0f, wx0 = 1.f - wx1;
  const float wy1 = iy - y0f, wy0 = 1.f - wy1;
  const float vx0 = (x0f >= 0.f && x0f <= (float)(W_ - 1)) ? 1.f : 0.f;
  const float vx1 = (x1f >= 0.f && x1f <= (float)(W_ - 1)) ? 1.f : 0.f;
  const float vy0 = (y0f >= 0.f && y0f <= (float)(H_ - 1)) ? 1.f : 0.f;
  const float vy1 = (y1f >= 0.f && y1f <= (float)(H_ - 1)) ? 1.f : 0.f;
  const int xi0 = (int)fminf(fmaxf(x0f, 0.f), (float)(W_ - 1));
  const int xi1 = (int)fminf(fmaxf(x1f, 0.f), (float)(W_ - 1));
  const int yi0 = (int)fminf(fmaxf(y0f, 0.f), (float)(H_ - 1));
  const int yi1 = (int)fminf(fmaxf(y1f, 0.f), (float)(H_ - 1));
  const float w00 = wx0 * wy0 * vx0 * vy0;
  const float w10 = wx1 * wy0 * vx1 * vy0;
  const float w01 = wx0 * wy1 * vx0 * vy1;
  const float w11 = wx1 * wy1 * vx1 * vy1;
  // lane l holds weights for depth l&31, x-column l>>5:
  const float wA_pre = (lane >= 32) ? w10 : w00;   // row y0
  const float wB_pre = (lane >= 32) ? w11 : w01;   // row y1
  // pack: bits 8..20 = (yi0*W+xi0)*256 (byte idx, f16), bit30 = xstep, bit31 = ystep
  const unsigned packed = (unsigned)((yi0 * W_ + xi0) * 256)
                        | ((unsigned)(xi1 - xi0) << 30)
                        | ((unsigned)(yi1 - yi0) << 31);

  const unsigned laneoff = (unsigned)(cl * 16);

#define LOAD_DEPTH(d) ({                                                     \
    const unsigned pk  = (unsigned)__builtin_amdgcn_readlane((int)packed, (d)); \
    const unsigned sbi = pk & 0x3FFFFFu;                                     \
    const unsigned sdx = (pk >> 22) & 256u;                                  \
    const unsigned sdy = ((unsigned)((int)pk >> 31)) & 32768u;               \
    const unsigned voff = sbi + (mx & sdx) + (my & sdy) + laneoff;           \
    *(const half8_t*)(F1b + voff); })

  float acc[32];
  half8_t buf0[8], buf1[8];
#pragma unroll
  for (int j = 0; j < 8; ++j) buf0[j] = LOAD_DEPTH(j);
#pragma unroll
  for (int dc = 0; dc < 4; ++dc) {
    half8_t* cur = (dc & 1) ? buf1 : buf0;
    half8_t* nxt = (dc & 1) ? buf0 : buf1;
    if (dc < 3) {
#pragma unroll
      for (int j = 0; j < 8; ++j) nxt[j] = LOAD_DEPTH(dc * 8 + 8 + j);
    }
#pragma unroll
    for (int j = 0; j < 8; ++j) {
      const half8_t s = cur[j];
      float dt = fdot2f(__builtin_shufflevector(s, s, 0, 1), f0a, 0.f);
      dt = fdot2f(__builtin_shufflevector(s, s, 2, 3), f0b_, dt);
      dt = fdot2f(__builtin_shufflevector(s, s, 4, 5), f0c, dt);
      dt = fdot2f(__builtin_shufflevector(s, s, 6, 7), f0d, dt);
      acc[dc * 8 + j] = dt;
    }
  }
#undef LOAD_DEPTH

  // ---- butterfly: fold channel bits first (xor 1,2,4,8) ----
  // stage xor m consumes array MSB-half into lane bit log2(m)
  float a16[16];
#pragma unroll
  for (int j = 0; j < 16; ++j) {
    const bool hi = (lane & 1) != 0;
    const float keep = hi ? acc[j + 16] : acc[j];
    const float send = hi ? acc[j] : acc[j + 16];
    a16[j] = keep + __shfl_xor(send, 1, 64);
  }
  float a8[8];
#pragma unroll
  for (int j = 0; j < 8; ++j) {
    const bool hi = (lane & 2) != 0;
    const float keep = hi ? a16[j + 8] : a16[j];
    const float send = hi ? a16[j] : a16[j + 8];
    a8[j] = keep + __shfl_xor(send, 2, 64);
  }
  float a4[4];
#pragma unroll
  for (int j = 0; j < 4; ++j) {
    const bool hi = (lane & 4) != 0;
    const float keep = hi ? a8[j + 4] : a8[j];
    const float send = hi ? a8[j] : a8[j + 4];
    a4[j] = keep + __shfl_xor(send, 4, 64);
  }
  float a2[2];
#pragma unroll
  for (int j = 0; j < 2; ++j) {
    const bool hi = (lane & 8) != 0;
    const float keep = hi ? a4[j + 2] : a4[j];
    const float send = hi ? a4[j] : a4[j + 2];
    a2[j] = keep + __shfl_xor(send, 8, 64);
  }

  // now: lane bits {0,1,2,3} = depth bits {4,3,2,1}; array idx = depth bit 0;
  // lane bit4 = x-corner, bit5 = y-row (unreduced). Apply weights via bpermute.
  {
    const int dbase = ((lane & 1) << 4) | (((lane >> 1) & 1) << 3)
                    | (((lane >> 2) & 1) << 2) | (((lane >> 3) & 1) << 1);
    const int xsel = (lane >> 4) & 1;
    const bool rowy1 = (lane & 32) != 0;
#pragma unroll
    for (int i = 0; i < 2; ++i) {
      const int idx = (xsel * 32 + dbase + i) * 4;
      const float wa = bperm_f(idx, wA_pre);
      const float wb = bperm_f(idx, wB_pre);
      a2[i] *= rowy1 ? wb : wa;
    }
  }

  // fold x-corner (xor16): depth bit0 -> lane bit4
  float v1;
  {
    const bool hi = (lane & 16) != 0;
    const float keep = hi ? a2[1] : a2[0];
    const float send = hi ? a2[0] : a2[1];
    v1 = keep + __shfl_xor(send, 16, 64);
  }
  // fold y-row (xor32)
  v1 += __shfl_xor(v1, 32, 64);

  if (lane < 32) {
    const int d = ((lane & 1) << 4) | (((lane >> 1) & 1) << 3)
                | (((lane >> 2) & 1) << 2) | (((lane >> 3) & 1) << 1)
                | ((lane >> 4) & 1);
    out[(((size_t)n * D_ + d) * H_ + h) * W_ + w] = v1 * 0.08838834764831845f; // 1/sqrt(128)
  }
}

extern "C" void kernel_launch(void* const* d_in, const int* in_sizes, int n_in,
                              void* d_out, int out_size, void* d_ws, size_t ws_size,
                              hipStream_t stream) {
  const float* features = (const float*)d_in[0];
  const float* extr     = (const float*)d_in[1];
  const float* nearp    = (const float*)d_in[2];
  const float* farp     = (const float*)d_in[3];
  float* out = (float*)d_out;
  _Float16* T = (_Float16*)d_ws;

  hipLaunchKernelGGL(transpose_kernel, dim3(V_ * H_ * 2), dim3(256), 0, stream, features, T);
  hipLaunchKernelGGL(corr_kernel, dim3(PIXELS / 4), dim3(256), 0, stream,
                     T, extr, nearp, farp, out);
}